// Round 2
// baseline (1499.801 us; speedup 1.0000x reference)
//
#include <hip/hip_runtime.h>
#include <math.h>

#define BB 64
#define TT 1024
#define KK 128
#define START_TAG 126
#define STOP_TAG 127

typedef float v2f __attribute__((ext_vector_type(2)));
typedef float v4f __attribute__((ext_vector_type(4)));

// Single-wave forward algorithm: ZERO barriers in the t-loop.
// Lane l owns rows r0=2l, r0+1. E = exp(T - rowmax) lives entirely in VGPRs
// (64 v4f per row-pair = 256 VGPRs; __launch_bounds__(64,1) -> 512 budget).
// Per step:
//   e broadcast: 32 uniform-address ds_read_b128 of the 512B e-vector
//   matvec:      128 v_pk_fma in-lane -> FULL dots d_{r0}, d_{r0+1} (no reduce!)
//   e'_j = d_j * F[t][j] * (1/s_prev)  with F = exp(feat + rowmax) computed
//          inline off-chain; s_prev = lag-1 divisor (exact: M += log(s_prev))
//   s broadcast: v_readlane(d0, 63)  (lane 63 row 126 = START row, E=all-ones)
//   all-gather:  one conflict-free ds_write_b64; wave-synchronous lgkmcnt only.
// Feats: depth-4 register prefetch pipeline (coalesced 8B/lane/step), no LDS
// staging, no chunk structure, no vmcnt(0) drains.
__global__ __launch_bounds__(64, 1) void crf_forward(
    const float* __restrict__ feats,   // [B,T,K]
    const int*   __restrict__ tags,    // [B,T]
    const int*   __restrict__ lens,    // [B]
    const float* __restrict__ trans,   // [K,K]
    float*       __restrict__ out_pb)  // [B]: forward_score - gold_score
{
  __shared__ __align__(16) float e_lds[KK];   // 512 B — the only LDS

  const int l  = threadIdx.x;                 // 0..63
  const int b  = blockIdx.x;
  const int r0 = 2 * l;
  const int L  = lens[b];
  const float* fb = feats + (size_t)b * TT * KK;

  // ---- pass 1: row maxima (streaming, nothing kept live) ----
  float mT0 = -INFINITY, mT1 = -INFINITY;
  {
    const v4f* t0 = (const v4f*)(trans + (size_t)r0 * KK);
    const v4f* t1 = (const v4f*)(trans + (size_t)(r0 + 1) * KK);
    #pragma unroll
    for (int i = 0; i < 32; ++i) {
      v4f a = t0[i], c = t1[i];
      mT0 = fmaxf(mT0, fmaxf(fmaxf(a[0], a[1]), fmaxf(a[2], a[3])));
      mT1 = fmaxf(mT1, fmaxf(fmaxf(c[0], c[1]), fmaxf(c[2], c[3])));
    }
  }
  // ---- pass 2: E = exp(T - mT) into registers (trans is L2-hot now) ----
  v4f E0[32], E1[32];
  {
    const v4f* t0 = (const v4f*)(trans + (size_t)r0 * KK);
    const v4f* t1 = (const v4f*)(trans + (size_t)(r0 + 1) * KK);
    #pragma unroll
    for (int i = 0; i < 32; ++i) {
      v4f a = t0[i], c = t1[i], o, p;
      o[0] = __expf(a[0] - mT0); o[1] = __expf(a[1] - mT0);
      o[2] = __expf(a[2] - mT0); o[3] = __expf(a[3] - mT0);
      p[0] = __expf(c[0] - mT1); p[1] = __expf(c[1] - mT1);
      p[2] = __expf(c[2] - mT1); p[3] = __expf(c[3] - mT1);
      E0[i] = o; E1[i] = p;
    }
  }

  // ---- init: e0 = onehot(START) (lane 63 holds rows 126,127) ----
  v2f ev; ev[0] = (l == 63) ? 1.0f : 0.0f; ev[1] = 0.0f;
  *(v2f*)(e_lds + r0) = ev;
  float M = fb[START_TAG];
  float s_prev = 1.0f, r = 1.0f;

  // ---- depth-4 feat prefetch pipeline (rows t=1..4; t<TT always) ----
  v2f p0 = *(const v2f*)(fb + (size_t)1 * KK + r0);
  v2f p1 = *(const v2f*)(fb + (size_t)2 * KK + r0);
  v2f p2 = *(const v2f*)(fb + (size_t)3 * KK + r0);
  v2f p3 = *(const v2f*)(fb + (size_t)4 * KK + r0);

  // ---- main recurrence: one wave, wave-synchronous LDS, no barriers ----
  #pragma unroll 4
  for (int t = 1; t < L; ++t) {
    // F multipliers (off the e-chain: depend on p0 and lag-1 r only)
    float rF0 = __expf(p0[0] + mT0) * r;
    float rF1 = __expf(p0[1] + mT1) * r;
    // rotate pipeline, issue prefetch for t+4 (clamped in-bounds)
    p0 = p1; p1 = p2; p2 = p3;
    {
      int tn = t + 4; tn = (tn < TT) ? tn : (TT - 1);
      p3 = *(const v2f*)(fb + (size_t)tn * KK + r0);
    }

    // full matvec: broadcast-read e (uniform addr), 128 pk_fma in-lane
    const v4f* eb = (const v4f*)e_lds;
    v4f a0 = {0.f,0.f,0.f,0.f}, a1 = a0, a2 = a0, a3 = a0;
    v4f c0 = a0, c1 = a0, c2 = a0, c3 = a0;
    #pragma unroll
    for (int i = 0; i < 8; ++i) {
      v4f e0 = eb[4*i], e1 = eb[4*i+1], e2 = eb[4*i+2], e3 = eb[4*i+3];
      a0 += e0 * E0[4*i];   a1 += e1 * E0[4*i+1];
      a2 += e2 * E0[4*i+2]; a3 += e3 * E0[4*i+3];
      c0 += e0 * E1[4*i];   c1 += e1 * E1[4*i+1];
      c2 += e2 * E1[4*i+2]; c3 += e3 * E1[4*i+3];
    }
    v4f av = (a0 + a1) + (a2 + a3);
    v4f cv = (c0 + c1) + (c2 + c3);
    float d0 = (av[0] + av[1]) + (av[2] + av[3]);
    float d1 = (cv[0] + cv[1]) + (cv[2] + cv[3]);

    M += __logf(s_prev);                       // off-chain, uniform
    ev[0] = d0 * rF0; ev[1] = d1 * rF1;
    // s for next step: lane 63's d0 is d_START = sum_k e_k (E row = all 1s)
    s_prev = __int_as_float(__builtin_amdgcn_readlane(__float_as_int(d0), 63));
    r = __builtin_amdgcn_rcpf(s_prev);
    *(v2f*)(e_lds + r0) = ev;                  // conflict-free all-gather
  }

  // ---- terminal: fwd = M + log(sum_k e_k) (ev regs hold final e) ----
  float sm = ev[0] + ev[1];
  #pragma unroll
  for (int m = 1; m < 64; m <<= 1) sm += __shfl_xor(sm, m, 64);
  const float fwd = M + __logf(sm);

  // ---- gold score (trans is L2-resident; 16 iters of independent loads) ----
  float g = 0.f;
  const int* tg = tags + b * TT;
  for (int t = l; t < TT; t += 64) {
    if (t < L)     g += fb[(size_t)t * KK + tg[t]];
    if (t < L - 1) g += trans[(size_t)tg[t + 1] * KK + tg[t]];
  }
  #pragma unroll
  for (int m = 1; m < 64; m <<= 1) g += __shfl_xor(g, m, 64);
  if (l == 0) out_pb[b] = fwd - g;
}

__global__ void crf_mean(const float* __restrict__ pb, float* __restrict__ out) {
  int tid = threadIdx.x;  // 64 threads, one wave
  float v = pb[tid];
  #pragma unroll
  for (int m = 1; m < 64; m <<= 1) v += __shfl_xor(v, m, 64);
  if (tid == 0) out[0] = v * (1.0f / 64.0f);
}

extern "C" void kernel_launch(void* const* d_in, const int* in_sizes, int n_in,
                              void* d_out, int out_size, void* d_ws, size_t ws_size,
                              hipStream_t stream) {
  const float* feats = (const float*)d_in[0];
  const int*   tags  = (const int*)d_in[1];
  const int*   lens  = (const int*)d_in[2];
  const float* trans = (const float*)d_in[3];
  float* pb = (float*)d_ws;   // 64 floats of scratch
  crf_forward<<<BB, 64, 0, stream>>>(feats, tags, lens, trans, pb);
  crf_mean<<<1, 64, 0, stream>>>(pb, (float*)d_out);
}

// Round 7
// 666.705 us; speedup vs baseline: 2.2496x; 2.2496x over previous
//
#include <hip/hip_runtime.h>
#include <math.h>

#define BB 64
#define TT 1024
#define KK 128
#define START_TAG 126
#define STOP_TAG 127
#define NTH 128      // 2 waves; lane tid owns row j = tid (full 128-wide dot in-lane)
#define CS 32        // timesteps of raw feats staged per chunk (16 KB LDS x2)

typedef float v4f __attribute__((ext_vector_type(4)));

// Raw workgroup barrier WITHOUT the vmcnt(0) drain __syncthreads performs.
// We only need LDS ordering (the e/s exchange); global feat prefetch loads
// stay in flight across step barriers (counted-wait discipline, T4-style).
__device__ __forceinline__ void step_barrier() {
  asm volatile("s_waitcnt lgkmcnt(0)" ::: "memory");  // own LDS writes visible
  __builtin_amdgcn_s_barrier();
  asm volatile("" ::: "memory");                      // no hoisting reads above
}

// Forward algorithm, log/exp-free inner chain, lag-1 normalization.
// Lane tid owns row j=tid: E_row = exp(T[j][:] - maxT_j) in 32 v4f (128 VGPR).
// Per step (one barrier, no cross-lane reduce):
//   e broadcast: 32 uniform-address ds_read_b128 (conflict-free broadcast)
//   d_j = dot(E_row, e)                 (64 pk_fma in-lane -> full dot)
//   e'_j = d_j * exp(feat[t][j]+maxT_j) * rcp(s_prev)   (off-chain factors)
//   s' = d_START (lane 126: START row of E is all-ones => d = sum_k e_k)
//   all-gather: one ds_write_b32 per lane (conflict-free), raw barrier.
// Feats staged per 32-step chunk: regs -> LDS (Fraw), prefetch for c+1 issued
// at chunk top and left outstanding across all step barriers.
__global__ __launch_bounds__(NTH, 1) void crf_forward(
    const float* __restrict__ feats,   // [B,T,K]
    const int*   __restrict__ tags,    // [B,T]
    const int*   __restrict__ lens,    // [B]
    const float* __restrict__ trans,   // [K,K]
    float*       __restrict__ out_pb)  // [B]: forward_score - gold_score
{
  __shared__ __align__(16) float ebuf[2][KK];       // double-buffered e
  __shared__ float sbuf[2];                         // double-buffered divisor
  __shared__ __align__(16) float Fraw[2][CS * KK];  // 2 x 16 KB raw feats
  __shared__ float wsum[2];

  const int tid = threadIdx.x;                      // 0..127 == owned row
  const int b   = blockIdx.x;
  const int L   = lens[b];
  const float* fb = feats + (size_t)b * TT * KK;

  // ---- E row into registers: one pass load + max, then exp in place ----
  v4f E[32];
  float mT = -INFINITY;
  {
    const v4f* tr = (const v4f*)(trans + (size_t)tid * KK);
    #pragma unroll
    for (int i = 0; i < 32; ++i) {
      v4f v = tr[i];
      E[i] = v;
      mT = fmaxf(mT, fmaxf(fmaxf(v[0], v[1]), fmaxf(v[2], v[3])));
    }
    #pragma unroll
    for (int i = 0; i < 32; ++i) {
      v4f v = E[i], o;
      o[0] = __expf(v[0] - mT); o[1] = __expf(v[1] - mT);
      o[2] = __expf(v[2] - mT); o[3] = __expf(v[3] - mT);
      E[i] = o;
    }
  }

  // ---- init: e0 = onehot(START), s0 = 1, M0 = feats[b,0,START] ----
  float ev = (tid == START_TAG) ? 1.0f : 0.0f;      // lane's own e_j
  ebuf[0][tid] = ev;
  if (tid == 0) sbuf[0] = 1.0f;
  float M = fb[START_TAG];                          // uniform across lanes

  // ---- prefetch chunk 0 raw feats into registers (8 x float4, coalesced) ----
  float4 pf[8];
  {
    const float4* s4 = (const float4*)fb;
    #pragma unroll
    for (int i = 0; i < 8; ++i) pf[i] = s4[i * NTH + tid];
  }

  // ---- chunked main recurrence ----
  int p = 0;
  for (int c = 0; c * CS < L; ++c) {
    // stage current chunk regs -> LDS (compiler inserts the vmcnt wait here;
    // pf loads were issued a full chunk ago, so the wait is ~free after c=0)
    float4* Fb4 = (float4*)Fraw[c & 1];
    #pragma unroll
    for (int i = 0; i < 8; ++i) Fb4[i * NTH + tid] = pf[i];
    // issue prefetch for chunk c+1; stays outstanding across step barriers
    if ((c + 1) * CS < L) {
      const float4* s4 = (const float4*)(fb + (size_t)(c + 1) * CS * KK);
      #pragma unroll
      for (int i = 0; i < 8; ++i) pf[i] = s4[i * NTH + tid];
    }
    step_barrier();                                 // Fraw (+init at c=0) visible

    const float* Fc = Fraw[c & 1];
    const int t_end = (L < (c + 1) * CS) ? L : (c + 1) * CS;
    for (int t = (c == 0) ? 1 : c * CS; t < t_end; ++t) {
      // off-chain factors first: stale divisor + raw feat
      const float sp = sbuf[p];
      const float Fr = Fc[(t & (CS - 1)) * KK + tid];
      float rr; asm("v_rcp_f32 %0, %1" : "=v"(rr) : "v"(sp));
      const float rF = __expf(Fr + mT) * rr;

      // full matvec: 32 uniform broadcast b128 reads, 64 pk_fma in-lane
      const v4f* eb = (const v4f*)ebuf[p];
      v4f a0 = {0.f,0.f,0.f,0.f}, a1 = a0, a2 = a0, a3 = a0;
      #pragma unroll
      for (int i = 0; i < 8; ++i) {
        a0 += eb[4*i + 0] * E[4*i + 0];
        a1 += eb[4*i + 1] * E[4*i + 1];
        a2 += eb[4*i + 2] * E[4*i + 2];
        a3 += eb[4*i + 3] * E[4*i + 3];
      }
      v4f av = (a0 + a1) + (a2 + a3);
      const float d = (av[0] + av[1]) + (av[2] + av[3]);

      ev = d * rF;
      ebuf[p ^ 1][tid] = ev;                        // conflict-free all-gather
      if (tid == START_TAG) sbuf[p ^ 1] = d;        // d_START = sum_k e_k
      M += __logf(sp);                              // off-chain, uniform
      p ^= 1;
      step_barrier();
    }
  }

  // ---- terminal: fwd = M + log(sum_j e_j) ----
  float sm = ev;
  #pragma unroll
  for (int m = 1; m < 64; m <<= 1) sm += __shfl_xor(sm, m, 64);
  if ((tid & 63) == 0) wsum[tid >> 6] = sm;
  step_barrier();
  const float fwd = M + __logf(wsum[0] + wsum[1]);
  step_barrier();                                   // protect wsum reuse

  // ---- gold score (trans/feats L2-hot; independent gathers) ----
  float g = 0.f;
  const int* tg = tags + b * TT;
  for (int t = tid; t < TT; t += NTH) {
    if (t < L)     g += fb[(size_t)t * KK + tg[t]];
    if (t < L - 1) g += trans[(size_t)tg[t + 1] * KK + tg[t]];
  }
  #pragma unroll
  for (int m = 1; m < 64; m <<= 1) g += __shfl_xor(g, m, 64);
  if ((tid & 63) == 0) wsum[tid >> 6] = g;
  step_barrier();
  if (tid == 0) out_pb[b] = fwd - (wsum[0] + wsum[1]);
}

__global__ void crf_mean(const float* __restrict__ pb, float* __restrict__ out) {
  int tid = threadIdx.x;  // 64 threads, one wave
  float v = pb[tid];
  #pragma unroll
  for (int m = 1; m < 64; m <<= 1) v += __shfl_xor(v, m, 64);
  if (tid == 0) out[0] = v * (1.0f / 64.0f);
}

extern "C" void kernel_launch(void* const* d_in, const int* in_sizes, int n_in,
                              void* d_out, int out_size, void* d_ws, size_t ws_size,
                              hipStream_t stream) {
  const float* feats = (const float*)d_in[0];
  const int*   tags  = (const int*)d_in[1];
  const int*   lens  = (const int*)d_in[2];
  const float* trans = (const float*)d_in[3];
  float* pb = (float*)d_ws;   // 64 floats of scratch
  crf_forward<<<BB, NTH, 0, stream>>>(feats, tags, lens, trans, pb);
  crf_mean<<<1, 64, 0, stream>>>(pb, (float*)d_out);
}